// Round 8
// baseline (185.163 us; speedup 1.0000x reference)
//
#include <hip/hip_runtime.h>
#include <stdint.h>

#pragma clang fp contract(off)

#define NCELL 49
#define NCLS  20
#define NSEG  16

struct Box { float x1, y1, x2, y2; };

__device__ __forceinline__ float sigmoid_ref(float x) {
#pragma clang fp contract(off)
  if (x >= 0.0f) {
    float z = expf(-x);
    return 1.0f / (1.0f + z);
  } else {
    float z = expf(x);
    return z / (1.0f + z);
  }
}

__device__ __forceinline__ float iou_box(Box a, Box b) {
#pragma clang fp contract(off)
  float lx = fmaxf(a.x1, b.x1);
  float ly = fmaxf(a.y1, b.y1);
  float rx = fminf(a.x2, b.x2);
  float ry = fminf(a.y2, b.y2);
  float w = fmaxf(rx - lx, 0.0f);
  float h = fmaxf(ry - ly, 0.0f);
  float inter = w * h;
  float aa = (a.x2 - a.x1) * (a.y2 - a.y1);
  float ab = (b.x2 - b.x1) * (b.y2 - b.y1);
  return inter / (aa + ab - inter);
}

__device__ __forceinline__ float permf(int dst, float v) {
  return __int_as_float(__builtin_amdgcn_ds_permute(dst << 2, __float_as_int(v)));
}
__device__ __forceinline__ unsigned mbcnt64(unsigned long long m) {
  return __builtin_amdgcn_mbcnt_hi((unsigned)(m >> 32),
         __builtin_amdgcn_mbcnt_lo((unsigned)m, 0u));
}

// One wave per image; 4 waves per block. Direct per-lane loads (inputs are
// L3-resident on replay — NOT memory-bound). NMS split into dependence-free
// candidate-mask (pipelined shuffles) + serial ballot resolve. Also emits
// per-(class,segment) (valid,tp) totals so the old k_apA dispatch vanishes.
__global__ __launch_bounds__(256) void k_per_image(
    const float* __restrict__ target, const float* __restrict__ output,
    uint8_t* __restrict__ entries, int* __restrict__ gt_count,
    unsigned* __restrict__ totals, int batch, int segimg)
{
#pragma clang fp contract(off)
  int lane = threadIdx.x & 63;
  int img  = blockIdx.x * 4 + (threadIdx.x >> 6);
  if (img >= batch) return;            // uniform per wave
  bool a = lane < NCELL;

  // ---- per-lane direct loads: 15+15 independent float2 (8B-aligned) ----
  float tv[30], ov[30];
  if (a) {
    const float2* T2 = (const float2*)(target + (size_t)img * 1470 + lane * 30);
    const float2* O2 = (const float2*)(output + (size_t)img * 1470 + lane * 30);
#pragma unroll
    for (int i = 0; i < 15; ++i) { float2 t = T2[i]; tv[2*i] = t.x; tv[2*i+1] = t.y; }
#pragma unroll
    for (int i = 0; i < 15; ++i) { float2 o = O2[i]; ov[2*i] = o.x; ov[2*i+1] = o.y; }
  } else {
#pragma unroll
    for (int i = 0; i < 30; ++i) { tv[i] = 0.0f; ov[i] = 0.0f; }
  }

  float fjx = (float)(lane % 7), fiy = (float)(lane / 7);

  // ---- ground truth (raw target, no sigmoid) ----
  int gcls = 0; float gx1 = 0, gy1 = 0, gx2 = 0, gy2 = 0; bool gval = false;
  if (a) {
    float tbv = tv[10];
#pragma unroll
    for (int c = 1; c < NCLS; ++c) { float v = tv[10 + c]; if (v > tbv) { tbv = v; gcls = c; } }
    gval = tv[4] > 0.5f;
    float cx = (tv[0] + fjx) * 64.0f, cy = (tv[1] + fiy) * 64.0f;
    float w2 = tv[2] * 448.0f, h2 = tv[3] * 448.0f;
    gx1 = cx - w2 * 0.5f; gy1 = cy - h2 * 0.5f;
    gx2 = cx + w2 * 0.5f; gy2 = cy + h2 * 0.5f;
  }
  unsigned long long gvmask = __ballot(a && gval);

  // ---- predictions (sigmoid everything, identical formula) ----
  float myc = -1.0f; int myk = 0; float px1 = 0, py1 = 0, px2 = 0, py2 = 0;
  if (a) {
#pragma unroll
    for (int i = 0; i < 30; ++i) ov[i] = sigmoid_ref(ov[i]);
    float c0 = ov[4], c1 = ov[9];
    myc = fmaxf(c0, c1);
    int resp = (c1 > c0) ? 1 : 0;      // first max wins
    float x = ov[resp * 5 + 0], y = ov[resp * 5 + 1];
    float ww = ov[resp * 5 + 2], hh = ov[resp * 5 + 3];
    float obv = ov[10];
#pragma unroll
    for (int c = 1; c < NCLS; ++c) { float v = ov[10 + c]; if (v > obv) { obv = v; myk = c; } }
    float cx = (x + fjx) * 64.0f, cy = (y + fiy) * 64.0f;
    float W = ww * 448.0f, H = hh * 448.0f;
    px1 = cx - W * 0.5f; py1 = cy - H * 0.5f;
    px2 = cx + W * 0.5f; py2 = cy + H * 0.5f;
  }

  // ---- stable rank (argsort(-conf), index tiebreak): pipelined shuffles ----
  int r = 0;
#pragma unroll 7
  for (int j = 0; j < NCELL; ++j) {
    float cj = __shfl(myc, j, 64);
    r += (cj > myc) || (cj == myc && j < lane);
  }
  r = a ? r : lane;                    // identity for pad lanes

  // ---- scatter to rank order ----
  float sx1 = permf(r, px1), sy1 = permf(r, py1);
  float sx2 = permf(r, px2), sy2 = permf(r, py2);
  float sconf = permf(r, myc);
  int   scls  = __builtin_amdgcn_ds_permute(r << 2, myk);
  Box myS; myS.x1 = sx1; myS.y1 = sy1; myS.x2 = sx2; myS.y2 = sy2;

  // ---- NMS phase 1: dependence-free candidate mask (pipelined) ----
  unsigned long long candmask = 0;
#pragma unroll 7
  for (int i = 0; i < NCELL; ++i) {
    Box bi;
    bi.x1 = __shfl(sx1, i, 64); bi.y1 = __shfl(sy1, i, 64);
    bi.x2 = __shfl(sx2, i, 64); bi.y2 = __shfl(sy2, i, 64);
    int ki = __shfl(scls, i, 64);
    float v = iou_box(myS, bi);
    if (a && (lane > i) && (scls == ki) && (v > 0.5f)) candmask |= (1ull << i);
  }

  // ---- NMS phase 2: serial resolve (ballot chain, ~6 cyc/iter) ----
  unsigned long long sup = 0;
#pragma unroll 1
  for (int i = 0; i < NCELL; ++i) {
    if (!((sup >> i) & 1ull)) {
      sup |= __ballot((candmask >> i) & 1ull);
    }
  }

  bool vp = a && !((sup >> lane) & 1ull) && (sconf > 0.5f);

  // ---- best same-class GT per pred (first-max; gvmask is loop-invariant) ----
  float mx = -1.0f; int best = 0;
#pragma unroll 1
  for (int g = 0; g < NCELL; ++g) {
    if (!((gvmask >> g) & 1ull)) continue;   // uniform, static mask
    int kg = __shfl(gcls, g, 64);
    Box bg;
    bg.x1 = __shfl(gx1, g, 64); bg.y1 = __shfl(gy1, g, 64);
    bg.x2 = __shfl(gx2, g, 64); bg.y2 = __shfl(gy2, g, 64);
    float v = iou_box(myS, bg);
    bool upd = a && (scls == kg) && (v > mx);
    if (upd) { mx = v; best = g; }
  }

  // ---- greedy TP assignment: uniform, redundant on all lanes ----
  unsigned long long vpmask = __ballot(vp);
  unsigned long long matched = 0, hits = 0;
#pragma unroll 1
  for (int i = 0; i < NCELL; ++i) {
    if (!((vpmask >> i) & 1ull)) continue;   // uniform
    float mxi = __shfl(mx, i, 64);
    int   bi  = __shfl(best, i, 64);
    if ((mxi > 0.5f) && !((matched >> bi) & 1ull)) {
      matched |= 1ull << bi;
      hits    |= 1ull << i;
    }
  }

  if (a) {
    entries[(size_t)img * NCELL + lane] =
        (uint8_t)(scls | (vp ? 32 : 0) | (((hits >> lane) & 1ull) ? 64 : 0));
  }

  // ---- per-class stats: gt_count + (valid,tp) packed totals per segment ----
  {
    int seg = img / segimg;
    int gcnt = 0; unsigned pkt = 0;
#pragma unroll 1
    for (int c = 0; c < NCLS; ++c) {
      unsigned long long gm = __ballot(a && gval && (gcls == c));
      unsigned long long pm = __ballot(a && (scls == c));
      if (lane == c) {
        gcnt = (int)__popcll(gm);
        pkt  = ((unsigned)__popcll(pm & vpmask) << 16) |
                (unsigned)__popcll(pm & hits);
      }
    }
    if (lane < NCLS) {
      if (gcnt) atomicAdd(&gt_count[lane], gcnt);
      if (pkt)  atomicAdd(&totals[lane * NSEG + seg], pkt);
    }
  }
}

// Exact per-byte match: y bytes < 0x40, so per-byte (y+0x7f) sets bit7 iff
// y>=1 with NO cross-byte carry. m has 0x80 exactly where (b&0x3f)==want.
__device__ __forceinline__ unsigned match_mask(unsigned w, unsigned wantx4) {
  unsigned y = (w & 0x3f3f3f3fu) ^ wantx4;
  return ~(y + 0x7f7f7f7fu) & 0x80808080u;
}

__device__ __forceinline__ uint4 load_tile(const uint8_t* entries, int e, int e1, int ne) {
  uint4 w4 = make_uint4(0, 0, 0, 0);
  if (e < e1) {
    int p = e << 4;
    if (p + 16 <= ne) {
      w4 = *(const uint4*)(entries + p);
    } else {
      unsigned ws[4] = {0, 0, 0, 0};
      for (int k = 0; k < ne - p; ++k)
        ws[k >> 2] |= ((unsigned)entries[p + k]) << (8 * (k & 3));
      w4.x = ws[0]; w4.y = ws[1]; w4.z = ws[2]; w4.w = ws[3];
    }
  }
  return w4;
}

// One block per (class, segment). Global prefix comes from k_per_image's
// totals. Last block (fenced counter) does the final AP mean in-place.
__global__ __launch_bounds__(256) void k_apB(
    const uint8_t* __restrict__ entries, const unsigned* __restrict__ totals,
    const int* __restrict__ gt_count, double* __restrict__ partials,
    unsigned* __restrict__ counter, float* __restrict__ out,
    int ne, int segimg)
{
#pragma clang fp contract(off)
  int c = blockIdx.x / NSEG, s = blockIdx.x % NSEG;
  int tid = threadIdx.x, wid = tid >> 6, lane = tid & 63;
  float g2 = (float)gt_count[c] + 1e-6f;
  unsigned wantx4 = (32u + (unsigned)c) * 0x01010101u;

  int nel = (ne + 15) >> 4;
  int segel = segimg * NCELL / 16;     // segimg % 16 == 0 -> exact
  int se0 = s * segel; if (se0 > nel) se0 = nel;
  int se1 = se0 + segel; if (se1 > nel) se1 = nel;
  int elw = (se1 > se0) ? ((se1 - se0 + 3) >> 2) : 0;
  int e0 = se0 + wid * elw; if (e0 > se1) e0 = se1;
  int e1 = e0 + elw; if (e1 > se1) e1 = se1;
  int ntile = (e1 > e0) ? ((e1 - e0 + 63) >> 6) : 0;

  // global prefix from earlier segments of this class (exact integer counts)
  unsigned Jrun = 0, Trun = 0;
  for (int s2 = 0; s2 < s; ++s2) {
    unsigned t2 = totals[c * NSEG + s2];
    Jrun += t2 >> 16; Trun += t2 & 0xffffu;
  }

  // local phase A: per-wave totals within segment -> wave offsets
  unsigned mv = 0, mt = 0;
  for (int t = 0; t < ntile; ++t) {
    uint4 w4 = load_tile(entries, e0 + t * 64 + lane, e1, ne);
    unsigned wsv[4] = {w4.x, w4.y, w4.z, w4.w};
#pragma unroll
    for (int q = 0; q < 4; ++q) {
      unsigned m = match_mask(wsv[q], wantx4);
      mv += __popc(m);
      mt += __popc(m & (wsv[q] << 1));
    }
  }
  unsigned long long tot = ((unsigned long long)mv << 32) | (unsigned long long)mt;
#pragma unroll
  for (int d = 1; d < 64; d <<= 1) tot += __shfl_xor(tot, d, 64);
  __shared__ unsigned long long wt[4];
  __shared__ double wacc[4];
  __shared__ int islast;
  __shared__ float apf_s[NCLS];
  if (lane == 0) wt[wid] = tot;
  __syncthreads();
  for (int w2 = 0; w2 < wid; ++w2) {
    Jrun += (unsigned)(wt[w2] >> 32);
    Trun += (unsigned)(wt[w2] & 0xffffffffull);
  }

  // phase B: per-tile bit-plane prefix + sparse emit
  double acc = 0.0;
  for (int t = 0; t < ntile; ++t) {
    int e = e0 + t * 64 + lane;
    int p = e << 4;
    uint4 w4 = load_tile(entries, e, e1, ne);
    unsigned wsv[4] = {w4.x, w4.y, w4.z, w4.w};
    unsigned mm[4], tm[4];
    unsigned cv = 0, ct = 0;
#pragma unroll
    for (int q = 0; q < 4; ++q) {
      unsigned m = match_mask(wsv[q], wantx4);
      mm[q] = m; tm[q] = m & (wsv[q] << 1);
      cv += __popc(m); ct += __popc(tm[q]);
    }
    unsigned jexcl = 0, texcl = 0, jtt = 0, ttt = 0;
#pragma unroll
    for (int b = 0; b < 5; ++b) {
      unsigned long long mj = __ballot(((cv >> b) & 1u) != 0u);
      unsigned long long mk = __ballot(((ct >> b) & 1u) != 0u);
      jexcl += mbcnt64(mj) << b;
      texcl += mbcnt64(mk) << b;
      jtt   += (unsigned)__popcll(mj) << b;
      ttt   += (unsigned)__popcll(mk) << b;
    }
    unsigned jr = Jrun + jexcl;
    unsigned tr = Trun + texcl;
#pragma unroll
    for (int q = 0; q < 4; ++q) {
      unsigned m = mm[q];
      while (m) {
        unsigned bit = (unsigned)__builtin_ctz(m);
        m &= m - 1;
        ++jr;
        if (tm[q] & (1u << bit)) {
          ++tr;
          int pos = p + 4 * q + (int)(bit >> 3);
          float ft = (float)tr, fj = (float)jr;
          float r_cur  = ft / g2;
          float r_prev = (ft - 1.0f) / g2;
          float p_cur  = ft / (fj + 1e-6f);
          float p_prev = (pos == 0) ? 1.0f
                                    : (ft - 1.0f) / ((fj - 1.0f) + 1e-6f);
          acc += (double)((r_cur - r_prev) * (p_cur + p_prev) * 0.5f);
        }
      }
    }
    Jrun += jtt;
    Trun += ttt;
  }

  for (int d = 32; d > 0; d >>= 1) acc += __shfl_down(acc, d, 64);
  if (lane == 0) wacc[wid] = acc;
  __syncthreads();
  if (tid == 0) {
    double bp = wacc[0] + wacc[1] + wacc[2] + wacc[3];
    __hip_atomic_store(&partials[blockIdx.x], bp,
                       __ATOMIC_RELEASE, __HIP_MEMORY_SCOPE_AGENT);
    unsigned prev = __hip_atomic_fetch_add(counter, 1u,
                       __ATOMIC_ACQ_REL, __HIP_MEMORY_SCOPE_AGENT);
    islast = (prev == (unsigned)(NCLS * NSEG - 1)) ? 1 : 0;
  }
  __syncthreads();
  if (islast) {
    if (tid < NCLS) {
      double d2 = 0.0;
#pragma unroll
      for (int s2 = 0; s2 < NSEG; ++s2)
        d2 += __hip_atomic_load(&partials[tid * NSEG + s2],
                                __ATOMIC_ACQUIRE, __HIP_MEMORY_SCOPE_AGENT);
      apf_s[tid] = (float)d2;
    }
    __syncthreads();
    if (tid == 0) {
      float sf = 0.0f, nf = 0.0f;
      for (int cc = 0; cc < NCLS; ++cc)
        if (gt_count[cc] > 0) { sf += apf_s[cc]; nf += 1.0f; }
      out[0] = sf / fmaxf(nf, 1.0f);
    }
  }
}

extern "C" void kernel_launch(void* const* d_in, const int* in_sizes, int n_in,
                              void* d_out, int out_size, void* d_ws, size_t ws_size,
                              hipStream_t stream) {
  const float* target = (const float*)d_in[0];
  const float* output = (const float*)d_in[1];
  int batch = in_sizes[0] / (NCELL * 30);
  int ne = batch * NCELL;
  int segimg = (((batch + NSEG - 1) / NSEG) + 15) & ~15;  // 16-image aligned

  uint8_t*  entries  = (uint8_t*)d_ws;
  size_t offA = ((size_t)ne + 255) & ~(size_t)255;
  int*      gt_count = (int*)((char*)d_ws + offA);                 // 256 B
  unsigned* totals   = (unsigned*)((char*)d_ws + offA + 256);      // 1280 B
  unsigned* counter  = (unsigned*)((char*)d_ws + offA + 256 + 1280);
  double*   partials = (double*)((char*)d_ws + offA + 2048);       // 2560 B

  (void)hipMemsetAsync((char*)d_ws + offA, 0, 2048, stream);
  k_per_image<<<(batch + 3) / 4, 256, 0, stream>>>(
      target, output, entries, gt_count, totals, batch, segimg);
  k_apB<<<NCLS * NSEG, 256, 0, stream>>>(
      entries, totals, gt_count, partials, counter, (float*)d_out, ne, segimg);
}

// Round 9
// 166.378 us; speedup vs baseline: 1.1129x; 1.1129x over previous
//
#include <hip/hip_runtime.h>
#include <stdint.h>

#pragma clang fp contract(off)

#define NCELL 49
#define NCLS  20
#define NSEG  16

struct Box { float x1, y1, x2, y2; };

__device__ __forceinline__ float sigmoid_ref(float x) {
#pragma clang fp contract(off)
  if (x >= 0.0f) {
    float z = expf(-x);
    return 1.0f / (1.0f + z);
  } else {
    float z = expf(x);
    return z / (1.0f + z);
  }
}

__device__ __forceinline__ float iou_box(Box a, Box b) {
#pragma clang fp contract(off)
  float lx = fmaxf(a.x1, b.x1);
  float ly = fmaxf(a.y1, b.y1);
  float rx = fminf(a.x2, b.x2);
  float ry = fminf(a.y2, b.y2);
  float w = fmaxf(rx - lx, 0.0f);
  float h = fmaxf(ry - ly, 0.0f);
  float inter = w * h;
  float aa = (a.x2 - a.x1) * (a.y2 - a.y1);
  float ab = (b.x2 - b.x1) * (b.y2 - b.y1);
  return inter / (aa + ab - inter);
}

__device__ __forceinline__ float permf(int dst, float v) {
  return __int_as_float(__builtin_amdgcn_ds_permute(dst << 2, __float_as_int(v)));
}
__device__ __forceinline__ unsigned mbcnt64(unsigned long long m) {
  return __builtin_amdgcn_mbcnt_hi((unsigned)(m >> 32),
         __builtin_amdgcn_mbcnt_lo((unsigned)m, 0u));
}

// One wave per image; 4 waves/block; R5's exact structure (best measured:
// 84 us) + fused per-(seg,class) stats with line-friendly totals layout
// totals[seg*32+cls] (20 lanes -> 2 cache lines, not 20).
__global__ __launch_bounds__(256) void k_per_image(
    const float* __restrict__ target, const float* __restrict__ output,
    uint8_t* __restrict__ entries, int* __restrict__ gt_count,
    unsigned* __restrict__ totals, int batch, int segimg)
{
#pragma clang fp contract(off)
  int lane = threadIdx.x & 63;
  int img  = blockIdx.x * 4 + (threadIdx.x >> 6);
  if (img >= batch) return;            // uniform per wave
  bool a = lane < NCELL;

  // ---- per-lane direct loads: 15+15 independent float2 (8B-aligned) ----
  float tv[30], ov[30];
  if (a) {
    const float2* T2 = (const float2*)(target + (size_t)img * 1470 + lane * 30);
    const float2* O2 = (const float2*)(output + (size_t)img * 1470 + lane * 30);
#pragma unroll
    for (int i = 0; i < 15; ++i) { float2 t = T2[i]; tv[2*i] = t.x; tv[2*i+1] = t.y; }
#pragma unroll
    for (int i = 0; i < 15; ++i) { float2 o = O2[i]; ov[2*i] = o.x; ov[2*i+1] = o.y; }
  } else {
#pragma unroll
    for (int i = 0; i < 30; ++i) { tv[i] = 0.0f; ov[i] = 0.0f; }
  }

  float fjx = (float)(lane % 7), fiy = (float)(lane / 7);

  // ---- ground truth (raw target, no sigmoid) ----
  int gcls = 0; float gx1 = 0, gy1 = 0, gx2 = 0, gy2 = 0; bool gval = false;
  if (a) {
    float tbv = tv[10];
#pragma unroll
    for (int c = 1; c < NCLS; ++c) { float v = tv[10 + c]; if (v > tbv) { tbv = v; gcls = c; } }
    gval = tv[4] > 0.5f;
    float cx = (tv[0] + fjx) * 64.0f, cy = (tv[1] + fiy) * 64.0f;
    float w2 = tv[2] * 448.0f, h2 = tv[3] * 448.0f;
    gx1 = cx - w2 * 0.5f; gy1 = cy - h2 * 0.5f;
    gx2 = cx + w2 * 0.5f; gy2 = cy + h2 * 0.5f;
  }
  unsigned long long gvmask = __ballot(a && gval);

  // ---- predictions (sigmoid everything, identical formula) ----
  float myc = -1.0f; int myk = 0; float px1 = 0, py1 = 0, px2 = 0, py2 = 0;
  if (a) {
#pragma unroll
    for (int i = 0; i < 30; ++i) ov[i] = sigmoid_ref(ov[i]);
    float c0 = ov[4], c1 = ov[9];
    myc = fmaxf(c0, c1);
    int resp = (c1 > c0) ? 1 : 0;      // first max wins
    float x = ov[resp * 5 + 0], y = ov[resp * 5 + 1];
    float ww = ov[resp * 5 + 2], hh = ov[resp * 5 + 3];
    float obv = ov[10];
#pragma unroll
    for (int c = 1; c < NCLS; ++c) { float v = ov[10 + c]; if (v > obv) { obv = v; myk = c; } }
    float cx = (x + fjx) * 64.0f, cy = (y + fiy) * 64.0f;
    float W = ww * 448.0f, H = hh * 448.0f;
    px1 = cx - W * 0.5f; py1 = cy - H * 0.5f;
    px2 = cx + W * 0.5f; py2 = cy + H * 0.5f;
  }

  // ---- stable rank (argsort(-conf), index tiebreak) via shuffles ----
  int r = lane;
  if (a) {
    r = 0;
#pragma unroll 1
    for (int j = 0; j < NCELL; ++j) {
      float cj = __shfl(myc, j, 64);
      r += (cj > myc) || (cj == myc && j < lane);
    }
  }

  // ---- scatter to rank order: lane q ends up holding rank-q item ----
  float sx1 = permf(r, px1), sy1 = permf(r, py1);
  float sx2 = permf(r, px2), sy2 = permf(r, py2);
  float sconf = permf(r, myc);
  int   scls  = __builtin_amdgcn_ds_permute(r << 2, myk);
  Box myS; myS.x1 = sx1; myS.y1 = sy1; myS.x2 = sx2; myS.y2 = sy2;

  // ---- greedy class-aware NMS: uniform 64-bit suppression mask ----
  unsigned long long sup = 0;
#pragma unroll 1
  for (int i = 0; i < NCELL; ++i) {
    if ((sup >> i) & 1ull) continue;   // uniform branch
    int ki = __shfl(scls, i, 64);
    Box bi;
    bi.x1 = __shfl(sx1, i, 64); bi.y1 = __shfl(sy1, i, 64);
    bi.x2 = __shfl(sx2, i, 64); bi.y2 = __shfl(sy2, i, 64);
    float v = iou_box(myS, bi);
    bool s = a && (lane > i) && (scls == ki) && (v > 0.5f);
    sup |= __ballot(s);
  }

  bool vp = a && !((sup >> lane) & 1ull) && (sconf > 0.5f);

  // ---- best same-class GT per pred (first-max semantics) ----
  float mx = -1.0f; int best = 0;
#pragma unroll 1
  for (int g = 0; g < NCELL; ++g) {
    if (!((gvmask >> g) & 1ull)) continue;   // uniform branch
    int kg = __shfl(gcls, g, 64);
    Box bg;
    bg.x1 = __shfl(gx1, g, 64); bg.y1 = __shfl(gy1, g, 64);
    bg.x2 = __shfl(gx2, g, 64); bg.y2 = __shfl(gy2, g, 64);
    float v = iou_box(myS, bg);
    bool upd = a && (scls == kg) && (v > mx);
    if (upd) { mx = v; best = g; }
  }

  // ---- greedy TP assignment: uniform, redundant on all lanes ----
  unsigned long long vpmask = __ballot(vp);
  unsigned long long matched = 0, hits = 0;
#pragma unroll 1
  for (int i = 0; i < NCELL; ++i) {
    if (!((vpmask >> i) & 1ull)) continue;   // uniform
    float mxi = __shfl(mx, i, 64);
    int   bi  = __shfl(best, i, 64);
    if ((mxi > 0.5f) && !((matched >> bi) & 1ull)) {
      matched |= 1ull << bi;
      hits    |= 1ull << i;
    }
  }

  if (a) {
    entries[(size_t)img * NCELL + lane] =
        (uint8_t)(scls | (vp ? 32 : 0) | (((hits >> lane) & 1ull) ? 64 : 0));
  }

  // ---- per-class stats: gt_count + packed (valid,tp) totals per segment ----
  {
    int seg = img / segimg;
    int gcnt = 0; unsigned pkt = 0;
#pragma unroll 1
    for (int c = 0; c < NCLS; ++c) {
      unsigned long long gm = __ballot(a && gval && (gcls == c));
      unsigned long long pm = __ballot(a && (scls == c));
      if (lane == c) {
        gcnt = (int)__popcll(gm);
        pkt  = ((unsigned)__popcll(pm & vpmask) << 16) |
                (unsigned)__popcll(pm & hits);
      }
    }
    if (lane < NCLS) {
      if (gcnt) atomicAdd(&gt_count[lane], gcnt);
      if (pkt)  atomicAdd(&totals[seg * 32 + lane], pkt);   // 2 lines/op
    }
  }
}

// Exact per-byte match: y bytes < 0x40, so per-byte (y+0x7f) sets bit7 iff
// y>=1 with NO cross-byte carry. m has 0x80 exactly where (b&0x3f)==want.
__device__ __forceinline__ unsigned match_mask(unsigned w, unsigned wantx4) {
  unsigned y = (w & 0x3f3f3f3fu) ^ wantx4;
  return ~(y + 0x7f7f7f7fu) & 0x80808080u;
}

__device__ __forceinline__ uint4 load_tile(const uint8_t* entries, int e, int e1, int ne) {
  uint4 w4 = make_uint4(0, 0, 0, 0);
  if (e < e1) {
    int p = e << 4;
    if (p + 16 <= ne) {
      w4 = *(const uint4*)(entries + p);
    } else {
      unsigned ws[4] = {0, 0, 0, 0};
      for (int k = 0; k < ne - p; ++k)
        ws[k >> 2] |= ((unsigned)entries[p + k]) << (8 * (k & 3));
      w4.x = ws[0]; w4.y = ws[1]; w4.z = ws[2]; w4.w = ws[3];
    }
  }
  return w4;
}

// One block per (class, segment). Global prefix comes from k_per_image's
// totals. Last block (fenced counter) does the final AP mean in-place.
__global__ __launch_bounds__(256) void k_apB(
    const uint8_t* __restrict__ entries, const unsigned* __restrict__ totals,
    const int* __restrict__ gt_count, double* __restrict__ partials,
    unsigned* __restrict__ counter, float* __restrict__ out,
    int ne, int segimg)
{
#pragma clang fp contract(off)
  int c = blockIdx.x / NSEG, s = blockIdx.x % NSEG;
  int tid = threadIdx.x, wid = tid >> 6, lane = tid & 63;
  float g2 = (float)gt_count[c] + 1e-6f;
  unsigned wantx4 = (32u + (unsigned)c) * 0x01010101u;

  int nel = (ne + 15) >> 4;
  int segel = segimg * NCELL / 16;     // segimg % 16 == 0 -> exact
  int se0 = s * segel; if (se0 > nel) se0 = nel;
  int se1 = se0 + segel; if (se1 > nel) se1 = nel;
  int elw = (se1 > se0) ? ((se1 - se0 + 3) >> 2) : 0;
  int e0 = se0 + wid * elw; if (e0 > se1) e0 = se1;
  int e1 = e0 + elw; if (e1 > se1) e1 = se1;
  int ntile = (e1 > e0) ? ((e1 - e0 + 63) >> 6) : 0;

  // global prefix from earlier segments of this class (exact integer counts)
  unsigned Jrun = 0, Trun = 0;
  for (int s2 = 0; s2 < s; ++s2) {
    unsigned t2 = totals[s2 * 32 + c];
    Jrun += t2 >> 16; Trun += t2 & 0xffffu;
  }

  // local phase A: per-wave totals within segment -> wave offsets
  unsigned mv = 0, mt = 0;
  for (int t = 0; t < ntile; ++t) {
    uint4 w4 = load_tile(entries, e0 + t * 64 + lane, e1, ne);
    unsigned wsv[4] = {w4.x, w4.y, w4.z, w4.w};
#pragma unroll
    for (int q = 0; q < 4; ++q) {
      unsigned m = match_mask(wsv[q], wantx4);
      mv += __popc(m);
      mt += __popc(m & (wsv[q] << 1));
    }
  }
  unsigned long long tot = ((unsigned long long)mv << 32) | (unsigned long long)mt;
#pragma unroll
  for (int d = 1; d < 64; d <<= 1) tot += __shfl_xor(tot, d, 64);
  __shared__ unsigned long long wt[4];
  __shared__ double wacc[4];
  __shared__ int islast;
  __shared__ float apf_s[NCLS];
  if (lane == 0) wt[wid] = tot;
  __syncthreads();
  for (int w2 = 0; w2 < wid; ++w2) {
    Jrun += (unsigned)(wt[w2] >> 32);
    Trun += (unsigned)(wt[w2] & 0xffffffffull);
  }

  // phase B: per-tile bit-plane prefix + sparse emit
  double acc = 0.0;
  for (int t = 0; t < ntile; ++t) {
    int e = e0 + t * 64 + lane;
    int p = e << 4;
    uint4 w4 = load_tile(entries, e, e1, ne);
    unsigned wsv[4] = {w4.x, w4.y, w4.z, w4.w};
    unsigned mm[4], tm[4];
    unsigned cv = 0, ct = 0;
#pragma unroll
    for (int q = 0; q < 4; ++q) {
      unsigned m = match_mask(wsv[q], wantx4);
      mm[q] = m; tm[q] = m & (wsv[q] << 1);
      cv += __popc(m); ct += __popc(tm[q]);
    }
    unsigned jexcl = 0, texcl = 0, jtt = 0, ttt = 0;
#pragma unroll
    for (int b = 0; b < 5; ++b) {
      unsigned long long mj = __ballot(((cv >> b) & 1u) != 0u);
      unsigned long long mk = __ballot(((ct >> b) & 1u) != 0u);
      jexcl += mbcnt64(mj) << b;
      texcl += mbcnt64(mk) << b;
      jtt   += (unsigned)__popcll(mj) << b;
      ttt   += (unsigned)__popcll(mk) << b;
    }
    unsigned jr = Jrun + jexcl;
    unsigned tr = Trun + texcl;
#pragma unroll
    for (int q = 0; q < 4; ++q) {
      unsigned m = mm[q];
      while (m) {
        unsigned bit = (unsigned)__builtin_ctz(m);
        m &= m - 1;
        ++jr;
        if (tm[q] & (1u << bit)) {
          ++tr;
          int pos = p + 4 * q + (int)(bit >> 3);
          float ft = (float)tr, fj = (float)jr;
          float r_cur  = ft / g2;
          float r_prev = (ft - 1.0f) / g2;
          float p_cur  = ft / (fj + 1e-6f);
          float p_prev = (pos == 0) ? 1.0f
                                    : (ft - 1.0f) / ((fj - 1.0f) + 1e-6f);
          acc += (double)((r_cur - r_prev) * (p_cur + p_prev) * 0.5f);
        }
      }
    }
    Jrun += jtt;
    Trun += ttt;
  }

  for (int d = 32; d > 0; d >>= 1) acc += __shfl_down(acc, d, 64);
  if (lane == 0) wacc[wid] = acc;
  __syncthreads();
  if (tid == 0) {
    double bp = wacc[0] + wacc[1] + wacc[2] + wacc[3];
    __hip_atomic_store(&partials[blockIdx.x], bp,
                       __ATOMIC_RELEASE, __HIP_MEMORY_SCOPE_AGENT);
    unsigned prev = __hip_atomic_fetch_add(counter, 1u,
                       __ATOMIC_ACQ_REL, __HIP_MEMORY_SCOPE_AGENT);
    islast = (prev == (unsigned)(NCLS * NSEG - 1)) ? 1 : 0;
  }
  __syncthreads();
  if (islast) {
    if (tid < NCLS) {
      double d2 = 0.0;
#pragma unroll
      for (int s2 = 0; s2 < NSEG; ++s2)
        d2 += __hip_atomic_load(&partials[tid * NSEG + s2],
                                __ATOMIC_ACQUIRE, __HIP_MEMORY_SCOPE_AGENT);
      apf_s[tid] = (float)d2;
    }
    __syncthreads();
    if (tid == 0) {
      float sf = 0.0f, nf = 0.0f;
      for (int cc = 0; cc < NCLS; ++cc)
        if (gt_count[cc] > 0) { sf += apf_s[cc]; nf += 1.0f; }
      out[0] = sf / fmaxf(nf, 1.0f);
    }
  }
}

extern "C" void kernel_launch(void* const* d_in, const int* in_sizes, int n_in,
                              void* d_out, int out_size, void* d_ws, size_t ws_size,
                              hipStream_t stream) {
  const float* target = (const float*)d_in[0];
  const float* output = (const float*)d_in[1];
  int batch = in_sizes[0] / (NCELL * 30);
  int ne = batch * NCELL;
  int segimg = (((batch + NSEG - 1) / NSEG) + 15) & ~15;  // 16-image aligned

  uint8_t*  entries  = (uint8_t*)d_ws;
  size_t offA = ((size_t)ne + 255) & ~(size_t)255;
  int*      gt_count = (int*)((char*)d_ws + offA);                 // 256 B
  unsigned* totals   = (unsigned*)((char*)d_ws + offA + 256);      // 16*32*4 = 2048 B
  unsigned* counter  = (unsigned*)((char*)d_ws + offA + 256 + 2048);
  double*   partials = (double*)((char*)d_ws + offA + 4096);       // 2560 B

  (void)hipMemsetAsync((char*)d_ws + offA, 0, 4096, stream);
  k_per_image<<<(batch + 3) / 4, 256, 0, stream>>>(
      target, output, entries, gt_count, totals, batch, segimg);
  k_apB<<<NCLS * NSEG, 256, 0, stream>>>(
      entries, totals, gt_count, partials, counter, (float*)d_out, ne, segimg);
}

// Round 10
// 159.810 us; speedup vs baseline: 1.1586x; 1.0411x over previous
//
#include <hip/hip_runtime.h>
#include <stdint.h>

#pragma clang fp contract(off)

#define NCELL 49
#define NCLS  20
#define NSEG  16

struct Box { float x1, y1, x2, y2; };

// Bit-exact branchless sigmoid: for x>=0 old code did expf(-x) -> z, 1/(1+z);
// for x<0 expf(x) -> z, z/(1+z). -fabsf(x) equals -x / x respectively, so z
// is the identical float; numerator select reproduces both branches exactly.
__device__ __forceinline__ float sigmoid_ref(float x) {
#pragma clang fp contract(off)
  float z = expf(-fabsf(x));
  float num = (x >= 0.0f) ? 1.0f : z;
  return num / (1.0f + z);
}

__device__ __forceinline__ float iou_box(Box a, Box b) {
#pragma clang fp contract(off)
  float lx = fmaxf(a.x1, b.x1);
  float ly = fmaxf(a.y1, b.y1);
  float rx = fminf(a.x2, b.x2);
  float ry = fminf(a.y2, b.y2);
  float w = fmaxf(rx - lx, 0.0f);
  float h = fmaxf(ry - ly, 0.0f);
  float inter = w * h;
  float aa = (a.x2 - a.x1) * (a.y2 - a.y1);
  float ab = (b.x2 - b.x1) * (b.y2 - b.y1);
  return inter / (aa + ab - inter);
}

__device__ __forceinline__ unsigned mbcnt64(unsigned long long m) {
  return __builtin_amdgcn_mbcnt_hi((unsigned)(m >> 32),
         __builtin_amdgcn_mbcnt_lo((unsigned)m, 0u));
}
#define WSYNC() __builtin_amdgcn_wave_barrier()

// One wave per image; 4 waves/block. Per-wave LDS tables give broadcast
// (uniform-address) reads with immediate offsets; all hot loops branch-free
// and fully pipelined. Same math as R9 (absmax 0.0), different schedule.
__global__ __launch_bounds__(256) void k_per_image(
    const float* __restrict__ target, const float* __restrict__ output,
    uint8_t* __restrict__ entries, int* __restrict__ gt_count,
    unsigned* __restrict__ totals, int batch, int segimg)
{
#pragma clang fp contract(off)
  __shared__ float4 pbox[4][64];   // sorted pred boxes
  __shared__ int2   pcc [4][64];   // sorted (cls, conf-bits)
  __shared__ float4 gbox[4][64];   // GT boxes
  __shared__ int    gcv [4][64];   // GT cls | valid<<8
  __shared__ float  ctab[4][64];   // pre-sort conf (for rank)
  __shared__ float2 mtab[4][64];   // (mx, best-bits) per rank

  int tid = threadIdx.x;
  int lane = tid & 63;
  int w = tid >> 6;
  int img = blockIdx.x * 4 + w;
  if (img >= batch) return;          // uniform per wave
  bool a = lane < NCELL;

  // ---- per-lane direct loads: 15+15 independent float2 (8B-aligned) ----
  float tv[30], ov[30];
  if (a) {
    const float2* T2 = (const float2*)(target + (size_t)img * 1470 + lane * 30);
    const float2* O2 = (const float2*)(output + (size_t)img * 1470 + lane * 30);
#pragma unroll
    for (int i = 0; i < 15; ++i) { float2 t = T2[i]; tv[2*i] = t.x; tv[2*i+1] = t.y; }
#pragma unroll
    for (int i = 0; i < 15; ++i) { float2 o = O2[i]; ov[2*i] = o.x; ov[2*i+1] = o.y; }
  } else {
#pragma unroll
    for (int i = 0; i < 30; ++i) { tv[i] = 0.0f; ov[i] = 0.0f; }
  }

  float fjx = (float)(lane % 7), fiy = (float)(lane / 7);

  // ---- ground truth (raw target, no sigmoid) ----
  int gcls = 0; bool gval = false;
  {
    float tbv = tv[10];
#pragma unroll
    for (int c = 1; c < NCLS; ++c) { float v = tv[10 + c]; if (v > tbv) { tbv = v; gcls = c; } }
    gval = a && (tv[4] > 0.5f);
    float cx = (tv[0] + fjx) * 64.0f, cy = (tv[1] + fiy) * 64.0f;
    float w2 = tv[2] * 448.0f, h2 = tv[3] * 448.0f;
    gbox[w][lane] = make_float4(cx - w2 * 0.5f, cy - h2 * 0.5f,
                                cx + w2 * 0.5f, cy + h2 * 0.5f);
    gcv[w][lane] = gcls | (gval ? 256 : 0);
  }

  // ---- predictions (sigmoid everything, identical values) ----
  float myc = -1.0f; int myk = 0; float px1 = 0, py1 = 0, px2 = 0, py2 = 0;
  if (a) {
#pragma unroll
    for (int i = 0; i < 30; ++i) ov[i] = sigmoid_ref(ov[i]);
    float c0 = ov[4], c1 = ov[9];
    myc = fmaxf(c0, c1);
    int resp = (c1 > c0) ? 1 : 0;      // first max wins
    float x = ov[resp * 5 + 0], y = ov[resp * 5 + 1];
    float ww = ov[resp * 5 + 2], hh = ov[resp * 5 + 3];
    float obv = ov[10];
#pragma unroll
    for (int c = 1; c < NCLS; ++c) { float v = ov[10 + c]; if (v > obv) { obv = v; myk = c; } }
    float cx = (x + fjx) * 64.0f, cy = (y + fiy) * 64.0f;
    float W = ww * 448.0f, H = hh * 448.0f;
    px1 = cx - W * 0.5f; py1 = cy - H * 0.5f;
    px2 = cx + W * 0.5f; py2 = cy + H * 0.5f;
  }
  ctab[w][lane] = myc;
  WSYNC();

  // ---- stable rank (argsort(-conf), index tiebreak): broadcast LDS reads ----
  int r = 0;
#pragma unroll
  for (int j = 0; j < NCELL; ++j) {
    float cj = ctab[w][j];
    r += (cj > myc) || (cj == myc && j < lane);
  }
  r = a ? r : lane;                    // identity for pad lanes

  // ---- scatter to rank order via LDS write ----
  pbox[w][r] = make_float4(px1, py1, px2, py2);
  pcc[w][r]  = make_int2(myk, __float_as_int(myc));
  WSYNC();

  float4 sb4 = pbox[w][lane];
  int2   cc  = pcc[w][lane];
  Box myS; myS.x1 = sb4.x; myS.y1 = sb4.y; myS.x2 = sb4.z; myS.y2 = sb4.w;
  int scls = cc.x;
  float sconf = __int_as_float(cc.y);

  // ---- NMS phase 1: dependence-free candidate mask (full unroll) ----
  unsigned long long candmask = 0;
#pragma unroll
  for (int i = 0; i < NCELL; ++i) {
    float4 b4 = pbox[w][i];
    int ki = pcc[w][i].x;
    Box bi; bi.x1 = b4.x; bi.y1 = b4.y; bi.x2 = b4.z; bi.y2 = b4.w;
    float v = iou_box(myS, bi);
    bool s = a && (lane > i) && (scls == ki) && (v > 0.5f);
    candmask |= s ? (1ull << i) : 0ull;
  }

  // ---- NMS phase 2: branch-free serial resolve (scalar select chain) ----
  unsigned long long sup = 0;
#pragma unroll
  for (int i = 0; i < NCELL; ++i) {
    unsigned long long bi = __ballot(((candmask >> i) & 1ull) != 0ull);
    bool keep = ((sup >> i) & 1ull) == 0ull;   // wave-uniform
    sup |= keep ? bi : 0ull;
  }

  bool vp = a && !((sup >> lane) & 1ull) && (sconf > 0.5f);

  // ---- best same-class GT per pred: branch-free full unroll ----
  float mx = -1.0f; int best = 0;
#pragma unroll
  for (int g = 0; g < NCELL; ++g) {
    float4 b4 = gbox[w][g];
    int cv = gcv[w][g];
    Box bg; bg.x1 = b4.x; bg.y1 = b4.y; bg.x2 = b4.z; bg.y2 = b4.w;
    float v = iou_box(myS, bg);
    bool upd = a && (cv & 256) && (scls == (cv & 255)) && (v > mx);
    mx = upd ? v : mx;
    best = upd ? g : best;
  }
  mtab[w][lane] = make_float2(mx, __int_as_float(best));
  WSYNC();

  // ---- greedy TP assignment: branch-free, redundant on all lanes ----
  unsigned long long vpmask = __ballot(vp);
  unsigned long long matched = 0, hits = 0;
#pragma unroll 7
  for (int i = 0; i < NCELL; ++i) {
    float2 f2 = mtab[w][i];
    float mxi = f2.x;
    int bi = __float_as_int(f2.y);
    bool hit = ((vpmask >> i) & 1ull) && (mxi > 0.5f) && !((matched >> bi) & 1ull);
    matched |= hit ? (1ull << bi) : 0ull;
    hits    |= hit ? (1ull << i)  : 0ull;
  }

  if (a) {
    entries[(size_t)img * NCELL + lane] =
        (uint8_t)(scls | (vp ? 32 : 0) | (((hits >> lane) & 1ull) ? 64 : 0));
  }

  // ---- per-class stats: gt_count + packed (valid,tp) totals per segment ----
  {
    int seg = img / segimg;
    int gcnt = 0; unsigned pkt = 0;
#pragma unroll 1
    for (int c = 0; c < NCLS; ++c) {
      unsigned long long gm = __ballot(gval && (gcls == c));
      unsigned long long pm = __ballot(a && (scls == c));
      if (lane == c) {
        gcnt = (int)__popcll(gm);
        pkt  = ((unsigned)__popcll(pm & vpmask) << 16) |
                (unsigned)__popcll(pm & hits);
      }
    }
    if (lane < NCLS) {
      if (gcnt) atomicAdd(&gt_count[lane], gcnt);
      if (pkt)  atomicAdd(&totals[seg * 32 + lane], pkt);   // 2 lines/op
    }
  }
}

// Exact per-byte match: y bytes < 0x40, so per-byte (y+0x7f) sets bit7 iff
// y>=1 with NO cross-byte carry. m has 0x80 exactly where (b&0x3f)==want.
__device__ __forceinline__ unsigned match_mask(unsigned w, unsigned wantx4) {
  unsigned y = (w & 0x3f3f3f3fu) ^ wantx4;
  return ~(y + 0x7f7f7f7fu) & 0x80808080u;
}

__device__ __forceinline__ uint4 load_tile(const uint8_t* entries, int e, int e1, int ne) {
  uint4 w4 = make_uint4(0, 0, 0, 0);
  if (e < e1) {
    int p = e << 4;
    if (p + 16 <= ne) {
      w4 = *(const uint4*)(entries + p);
    } else {
      unsigned ws[4] = {0, 0, 0, 0};
      for (int k = 0; k < ne - p; ++k)
        ws[k >> 2] |= ((unsigned)entries[p + k]) << (8 * (k & 3));
      w4.x = ws[0]; w4.y = ws[1]; w4.z = ws[2]; w4.w = ws[3];
    }
  }
  return w4;
}

// One block per (class, segment). Global prefix comes from k_per_image's
// totals. Last block (fenced counter) does the final AP mean in-place.
__global__ __launch_bounds__(256) void k_apB(
    const uint8_t* __restrict__ entries, const unsigned* __restrict__ totals,
    const int* __restrict__ gt_count, double* __restrict__ partials,
    unsigned* __restrict__ counter, float* __restrict__ out,
    int ne, int segimg)
{
#pragma clang fp contract(off)
  int c = blockIdx.x / NSEG, s = blockIdx.x % NSEG;
  int tid = threadIdx.x, wid = tid >> 6, lane = tid & 63;
  float g2 = (float)gt_count[c] + 1e-6f;
  unsigned wantx4 = (32u + (unsigned)c) * 0x01010101u;

  int nel = (ne + 15) >> 4;
  int segel = segimg * NCELL / 16;     // segimg % 16 == 0 -> exact
  int se0 = s * segel; if (se0 > nel) se0 = nel;
  int se1 = se0 + segel; if (se1 > nel) se1 = nel;
  int elw = (se1 > se0) ? ((se1 - se0 + 3) >> 2) : 0;
  int e0 = se0 + wid * elw; if (e0 > se1) e0 = se1;
  int e1 = e0 + elw; if (e1 > se1) e1 = se1;
  int ntile = (e1 > e0) ? ((e1 - e0 + 63) >> 6) : 0;

  // global prefix from earlier segments of this class (exact integer counts)
  unsigned Jrun = 0, Trun = 0;
  for (int s2 = 0; s2 < s; ++s2) {
    unsigned t2 = totals[s2 * 32 + c];
    Jrun += t2 >> 16; Trun += t2 & 0xffffu;
  }

  // local phase A: per-wave totals within segment -> wave offsets
  unsigned mv = 0, mt = 0;
  for (int t = 0; t < ntile; ++t) {
    uint4 w4 = load_tile(entries, e0 + t * 64 + lane, e1, ne);
    unsigned wsv[4] = {w4.x, w4.y, w4.z, w4.w};
#pragma unroll
    for (int q = 0; q < 4; ++q) {
      unsigned m = match_mask(wsv[q], wantx4);
      mv += __popc(m);
      mt += __popc(m & (wsv[q] << 1));
    }
  }
  unsigned long long tot = ((unsigned long long)mv << 32) | (unsigned long long)mt;
#pragma unroll
  for (int d = 1; d < 64; d <<= 1) tot += __shfl_xor(tot, d, 64);
  __shared__ unsigned long long wt[4];
  __shared__ double wacc[4];
  __shared__ int islast;
  __shared__ float apf_s[NCLS];
  if (lane == 0) wt[wid] = tot;
  __syncthreads();
  for (int w2 = 0; w2 < wid; ++w2) {
    Jrun += (unsigned)(wt[w2] >> 32);
    Trun += (unsigned)(wt[w2] & 0xffffffffull);
  }

  // phase B: per-tile bit-plane prefix + sparse emit
  double acc = 0.0;
  for (int t = 0; t < ntile; ++t) {
    int e = e0 + t * 64 + lane;
    int p = e << 4;
    uint4 w4 = load_tile(entries, e, e1, ne);
    unsigned wsv[4] = {w4.x, w4.y, w4.z, w4.w};
    unsigned mm[4], tm[4];
    unsigned cv = 0, ct = 0;
#pragma unroll
    for (int q = 0; q < 4; ++q) {
      unsigned m = match_mask(wsv[q], wantx4);
      mm[q] = m; tm[q] = m & (wsv[q] << 1);
      cv += __popc(m); ct += __popc(tm[q]);
    }
    unsigned jexcl = 0, texcl = 0, jtt = 0, ttt = 0;
#pragma unroll
    for (int b = 0; b < 5; ++b) {
      unsigned long long mj = __ballot(((cv >> b) & 1u) != 0u);
      unsigned long long mk = __ballot(((ct >> b) & 1u) != 0u);
      jexcl += mbcnt64(mj) << b;
      texcl += mbcnt64(mk) << b;
      jtt   += (unsigned)__popcll(mj) << b;
      ttt   += (unsigned)__popcll(mk) << b;
    }
    unsigned jr = Jrun + jexcl;
    unsigned tr = Trun + texcl;
#pragma unroll
    for (int q = 0; q < 4; ++q) {
      unsigned m = mm[q];
      while (m) {
        unsigned bit = (unsigned)__builtin_ctz(m);
        m &= m - 1;
        ++jr;
        if (tm[q] & (1u << bit)) {
          ++tr;
          int pos = p + 4 * q + (int)(bit >> 3);
          float ft = (float)tr, fj = (float)jr;
          float r_cur  = ft / g2;
          float r_prev = (ft - 1.0f) / g2;
          float p_cur  = ft / (fj + 1e-6f);
          float p_prev = (pos == 0) ? 1.0f
                                    : (ft - 1.0f) / ((fj - 1.0f) + 1e-6f);
          acc += (double)((r_cur - r_prev) * (p_cur + p_prev) * 0.5f);
        }
      }
    }
    Jrun += jtt;
    Trun += ttt;
  }

  for (int d = 32; d > 0; d >>= 1) acc += __shfl_down(acc, d, 64);
  if (lane == 0) wacc[wid] = acc;
  __syncthreads();
  if (tid == 0) {
    double bp = wacc[0] + wacc[1] + wacc[2] + wacc[3];
    __hip_atomic_store(&partials[blockIdx.x], bp,
                       __ATOMIC_RELEASE, __HIP_MEMORY_SCOPE_AGENT);
    unsigned prev = __hip_atomic_fetch_add(counter, 1u,
                       __ATOMIC_ACQ_REL, __HIP_MEMORY_SCOPE_AGENT);
    islast = (prev == (unsigned)(NCLS * NSEG - 1)) ? 1 : 0;
  }
  __syncthreads();
  if (islast) {
    if (tid < NCLS) {
      double d2 = 0.0;
#pragma unroll
      for (int s2 = 0; s2 < NSEG; ++s2)
        d2 += __hip_atomic_load(&partials[tid * NSEG + s2],
                                __ATOMIC_ACQUIRE, __HIP_MEMORY_SCOPE_AGENT);
      apf_s[tid] = (float)d2;
    }
    __syncthreads();
    if (tid == 0) {
      float sf = 0.0f, nf = 0.0f;
      for (int cc = 0; cc < NCLS; ++cc)
        if (gt_count[cc] > 0) { sf += apf_s[cc]; nf += 1.0f; }
      out[0] = sf / fmaxf(nf, 1.0f);
    }
  }
}

extern "C" void kernel_launch(void* const* d_in, const int* in_sizes, int n_in,
                              void* d_out, int out_size, void* d_ws, size_t ws_size,
                              hipStream_t stream) {
  const float* target = (const float*)d_in[0];
  const float* output = (const float*)d_in[1];
  int batch = in_sizes[0] / (NCELL * 30);
  int ne = batch * NCELL;
  int segimg = (((batch + NSEG - 1) / NSEG) + 15) & ~15;  // 16-image aligned

  uint8_t*  entries  = (uint8_t*)d_ws;
  size_t offA = ((size_t)ne + 255) & ~(size_t)255;
  int*      gt_count = (int*)((char*)d_ws + offA);                 // 256 B
  unsigned* totals   = (unsigned*)((char*)d_ws + offA + 256);      // 2048 B
  unsigned* counter  = (unsigned*)((char*)d_ws + offA + 256 + 2048);
  double*   partials = (double*)((char*)d_ws + offA + 4096);       // 2560 B

  (void)hipMemsetAsync((char*)d_ws + offA, 0, 4096, stream);
  k_per_image<<<(batch + 3) / 4, 256, 0, stream>>>(
      target, output, entries, gt_count, totals, batch, segimg);
  k_apB<<<NCLS * NSEG, 256, 0, stream>>>(
      entries, totals, gt_count, partials, counter, (float*)d_out, ne, segimg);
}